// Round 5
// baseline (831.689 us; speedup 1.0000x reference)
//
#include <hip/hip_runtime.h>
#include <math.h>

#define BB   8
#define CCH  256
#define HH   112
#define HW   12544   // 112*112
#define LDK  40      // padded k-stride in shorts (32 + 8): 80B rows, 5*16B granules

typedef __attribute__((ext_vector_type(8))) short  bf16x8;
typedef __attribute__((ext_vector_type(4))) short  short4v;
typedef __attribute__((ext_vector_type(4))) float  f32x4;

__device__ __forceinline__ unsigned short f2bf_rne(float f) {
    unsigned u = __float_as_uint(f);
    return (unsigned short)((u + 0x7FFFu + ((u >> 16) & 1u)) >> 16);
}
__device__ __forceinline__ float bf2f(unsigned short h) {
    return __uint_as_float(((unsigned)h) << 16);
}

// Y[b][o][n] = sum_c W[o][c] * X[b][c][n], via split-bf16 MFMA (hi/lo, 3 terms).
// Optional epilogue: relu(Res + Y).
// Tile: 128(o) x 128(n) x BK=32, 256 threads = 4 waves (2x2 wave grid),
// each wave 64x64 = 4x4 fragments of mfma_f32_16x16x32_bf16.
__global__ __launch_bounds__(256) void conv_mfma(
    const float* __restrict__ Wm,
    const float* __restrict__ Xin,
    float* __restrict__ Yout,
    const float* __restrict__ Res)
{
    const int bn  = blockIdx.x;   // 0..97  pixel tile
    const int bm  = blockIdx.y;   // 0..1   out-channel tile
    const int b   = blockIdx.z;   // 0..7
    const int tid = threadIdx.x;

    // [hi/lo][row*LDK + k] ; rows: As=o(128), Bs=n(128); k=0..31
    __shared__ __align__(16) short As[2][128 * LDK];
    __shared__ __align__(16) short Bs[2][128 * LDK];

    const float* Xb = Xin + (size_t)b * CCH * HW;

    f32x4 acc[4][4];
#pragma unroll
    for (int m = 0; m < 4; ++m)
#pragma unroll
        for (int nf = 0; nf < 4; ++nf) acc[m][nf] = (f32x4){0.f, 0.f, 0.f, 0.f};

    // staging thread roles
    const int ao  = tid >> 1;            // A: o row 0..127
    const int akh = (tid & 1) << 4;      // A: k half 0 / 16
    const int bnp = tid & 31;            // B: n patch (4 cols)
    const int bcp = tid >> 5;            // B: c patch (4 rows) 0..7

    // wave/fragment roles
    const int lane = tid & 63;
    const int wid  = tid >> 6;
    const int wr = wid >> 1, wc = wid & 1;
    const int fr = lane & 15;            // m/n index within fragment
    const int fg = lane >> 4;            // k-group (8 elems each)

    for (int k0 = 0; k0 < CCH; k0 += 32) {
        // ---- stage A: W[bm*128+o][k0..k0+31] -> As hi/lo, k-contiguous ----
        {
            const float* wsrc = Wm + (size_t)(bm * 128 + ao) * CCH + k0 + akh;
            float4 w0 = *(const float4*)(wsrc + 0);
            float4 w1 = *(const float4*)(wsrc + 4);
            float4 w2 = *(const float4*)(wsrc + 8);
            float4 w3 = *(const float4*)(wsrc + 12);
            float wf[16] = {w0.x, w0.y, w0.z, w0.w, w1.x, w1.y, w1.z, w1.w,
                            w2.x, w2.y, w2.z, w2.w, w3.x, w3.y, w3.z, w3.w};
            bf16x8 h0, h1, l0, l1;
#pragma unroll
            for (int i = 0; i < 8; ++i) {
                unsigned short hb = f2bf_rne(wf[i]);
                h0[i] = (short)hb;
                l0[i] = (short)f2bf_rne(wf[i] - bf2f(hb));
            }
#pragma unroll
            for (int i = 0; i < 8; ++i) {
                unsigned short hb = f2bf_rne(wf[8 + i]);
                h1[i] = (short)hb;
                l1[i] = (short)f2bf_rne(wf[8 + i] - bf2f(hb));
            }
            *(bf16x8*)&As[0][ao * LDK + akh]     = h0;
            *(bf16x8*)&As[0][ao * LDK + akh + 8] = h1;
            *(bf16x8*)&As[1][ao * LDK + akh]     = l0;
            *(bf16x8*)&As[1][ao * LDK + akh + 8] = l1;
        }
        // ---- stage B: X[k0..k0+31][bn*128..+127] -> Bs[n][k] hi/lo ----
        // (4c x 4n fp32 patch per thread, register transpose during bf16 split)
        {
            const float* xsrc = Xb + (size_t)(k0 + bcp * 4) * HW + (size_t)bn * 128 + bnp * 4;
            float4 r0 = *(const float4*)(xsrc);
            float4 r1 = *(const float4*)(xsrc + HW);
            float4 r2 = *(const float4*)(xsrc + 2 * HW);
            float4 r3 = *(const float4*)(xsrc + 3 * HW);
            float rf[4][4] = {{r0.x, r0.y, r0.z, r0.w},
                              {r1.x, r1.y, r1.z, r1.w},
                              {r2.x, r2.y, r2.z, r2.w},
                              {r3.x, r3.y, r3.z, r3.w}};
#pragma unroll
            for (int j = 0; j < 4; ++j) {          // n offset within patch
                short4v hv, lv;
#pragma unroll
                for (int rr = 0; rr < 4; ++rr) {   // c offset within patch
                    unsigned short hb = f2bf_rne(rf[rr][j]);
                    hv[rr] = (short)hb;
                    lv[rr] = (short)f2bf_rne(rf[rr][j] - bf2f(hb));
                }
                *(short4v*)&Bs[0][(bnp * 4 + j) * LDK + bcp * 4] = hv;
                *(short4v*)&Bs[1][(bnp * 4 + j) * LDK + bcp * 4] = lv;
            }
        }
        __syncthreads();

        // ---- fragments + MFMA ----
        bf16x8 ah[4], al[4], bh[4], bl[4];
#pragma unroll
        for (int m = 0; m < 4; ++m) {
            const int off = (wr * 64 + m * 16 + fr) * LDK + fg * 8;
            ah[m] = *(const bf16x8*)&As[0][off];
            al[m] = *(const bf16x8*)&As[1][off];
        }
#pragma unroll
        for (int nf = 0; nf < 4; ++nf) {
            const int off = (wc * 64 + nf * 16 + fr) * LDK + fg * 8;
            bh[nf] = *(const bf16x8*)&Bs[0][off];
            bl[nf] = *(const bf16x8*)&Bs[1][off];
        }
#pragma unroll
        for (int m = 0; m < 4; ++m)
#pragma unroll
            for (int nf = 0; nf < 4; ++nf) {
                acc[m][nf] = __builtin_amdgcn_mfma_f32_16x16x32_bf16(ah[m], bh[nf], acc[m][nf], 0, 0, 0);
                acc[m][nf] = __builtin_amdgcn_mfma_f32_16x16x32_bf16(ah[m], bl[nf], acc[m][nf], 0, 0, 0);
                acc[m][nf] = __builtin_amdgcn_mfma_f32_16x16x32_bf16(al[m], bh[nf], acc[m][nf], 0, 0, 0);
            }
        __syncthreads();
    }

    // ---- epilogue: C/D layout col=lane&15, row=(lane>>4)*4+reg ----
#pragma unroll
    for (int m = 0; m < 4; ++m)
#pragma unroll
        for (int nf = 0; nf < 4; ++nf) {
            const int gcol = bn * 128 + wc * 64 + nf * 16 + fr;
#pragma unroll
            for (int q = 0; q < 4; ++q) {
                const int grow = bm * 128 + wr * 64 + m * 16 + fg * 4 + q;
                const size_t idx = ((size_t)b * CCH + grow) * HW + gcol;
                float v = acc[m][nf][q];
                if (Res) v = fmaxf(v + Res[idx], 0.f);
                Yout[idx] = v;
            }
        }
}

// One block per (b,c): S = Q@K (112x112), row-softmax, Z = M@V.  (fp32)
__global__ __launch_bounds__(256) void attn_kernel(
    const float* __restrict__ Qg,
    const float* __restrict__ Kg,
    const float* __restrict__ Vg,
    float* __restrict__ Zg)
{
    const int bc  = blockIdx.x;    // 0..2047
    const int tid = threadIdx.x;
    const int tx  = tid & 15;
    const int ty  = tid >> 4;

    __shared__ float Qs[HH][116];  // later reused to hold M
    __shared__ float Ks[HH][116];
    __shared__ float Vs[HH][116];

    const float* Qp = Qg + (size_t)bc * HW;
    const float* Kp = Kg + (size_t)bc * HW;
    const float* Vp = Vg + (size_t)bc * HW;

    for (int idx = tid; idx < HW / 4; idx += 256) {
        int row = idx / 28;
        int c4  = (idx % 28) * 4;
        *(float4*)&Qs[row][c4] = *(const float4*)(Qp + row * HH + c4);
        *(float4*)&Ks[row][c4] = *(const float4*)(Kp + row * HH + c4);
        *(float4*)&Vs[row][c4] = *(const float4*)(Vp + row * HH + c4);
    }
    __syncthreads();

    const int i0 = ty * 7;
    const int j0 = tx * 7;

    float s[7][7];
#pragma unroll
    for (int ii = 0; ii < 7; ++ii)
#pragma unroll
        for (int jj = 0; jj < 7; ++jj) s[ii][jj] = 0.f;

    for (int k = 0; k < HH; ++k) {
        float qv[7], kv[7];
#pragma unroll
        for (int ii = 0; ii < 7; ++ii) qv[ii] = Qs[i0 + ii][k];
#pragma unroll
        for (int jj = 0; jj < 7; ++jj) kv[jj] = Ks[k][j0 + jj];
#pragma unroll
        for (int ii = 0; ii < 7; ++ii)
#pragma unroll
            for (int jj = 0; jj < 7; ++jj)
                s[ii][jj] = fmaf(qv[ii], kv[jj], s[ii][jj]);
    }

#pragma unroll
    for (int ii = 0; ii < 7; ++ii) {
        float mx = s[ii][0];
#pragma unroll
        for (int jj = 1; jj < 7; ++jj) mx = fmaxf(mx, s[ii][jj]);
#pragma unroll
        for (int off = 1; off < 16; off <<= 1) mx = fmaxf(mx, __shfl_xor(mx, off));
        float sum = 0.f;
#pragma unroll
        for (int jj = 0; jj < 7; ++jj) {
            float e = __expf(s[ii][jj] - mx);
            s[ii][jj] = e;
            sum += e;
        }
#pragma unroll
        for (int off = 1; off < 16; off <<= 1) sum += __shfl_xor(sum, off);
        float inv = 1.0f / sum;
#pragma unroll
        for (int jj = 0; jj < 7; ++jj) s[ii][jj] *= inv;
    }

    __syncthreads();
#pragma unroll
    for (int ii = 0; ii < 7; ++ii)
#pragma unroll
        for (int jj = 0; jj < 7; ++jj)
            Qs[i0 + ii][j0 + jj] = s[ii][jj];   // M overwrites Q
    __syncthreads();

    float z[7][7];
#pragma unroll
    for (int ii = 0; ii < 7; ++ii)
#pragma unroll
        for (int ww = 0; ww < 7; ++ww) z[ii][ww] = 0.f;

    for (int j = 0; j < HH; ++j) {
        float mv[7], vv[7];
#pragma unroll
        for (int ii = 0; ii < 7; ++ii) mv[ii] = Qs[i0 + ii][j];
#pragma unroll
        for (int ww = 0; ww < 7; ++ww) vv[ww] = Vs[j][j0 + ww];
#pragma unroll
        for (int ii = 0; ii < 7; ++ii)
#pragma unroll
            for (int ww = 0; ww < 7; ++ww)
                z[ii][ww] = fmaf(mv[ii], vv[ww], z[ii][ww]);
    }

    float* Zp = Zg + (size_t)bc * HW;
#pragma unroll
    for (int ii = 0; ii < 7; ++ii)
#pragma unroll
        for (int ww = 0; ww < 7; ++ww)
            Zp[(i0 + ii) * HH + j0 + ww] = z[ii][ww];
}

extern "C" void kernel_launch(void* const* d_in, const int* in_sizes, int n_in,
                              void* d_out, int out_size, void* d_ws, size_t ws_size,
                              hipStream_t stream) {
    const float* x  = (const float*)d_in[0];
    const float* y  = (const float*)d_in[1];
    const float* WQ = (const float*)d_in[2];
    const float* WK = (const float*)d_in[3];
    const float* WV = (const float*)d_in[4];
    const float* WZ = (const float*)d_in[5];
    float* out = (float*)d_out;

    const size_t n = (size_t)BB * CCH * HW;   // 25,690,112 elements

    // Workspace (2*n floats = 205.5 MB):
    //   Q -> d_out (consumed by attn, then d_out fully rewritten by final conv)
    //   K -> ws[0..n), V -> ws[n..2n)
    //   Z -> aliases K buffer (each attn block stages its own K tile to LDS
    //        before writing its own Z region; regions are disjoint per block)
    float* Qb = out;
    float* Kb = (float*)d_ws;
    float* Vb = Kb + n;
    float* Zb = Kb;

    dim3 grid(98, 2, 8), blk(256);
    conv_mfma<<<grid, blk, 0, stream>>>(WQ, x, Qb, nullptr);
    conv_mfma<<<grid, blk, 0, stream>>>(WK, y, Kb, nullptr);
    conv_mfma<<<grid, blk, 0, stream>>>(WV, y, Vb, nullptr);
    attn_kernel<<<dim3(2048), blk, 0, stream>>>(Qb, Kb, Vb, Zb);
    conv_mfma<<<grid, blk, 0, stream>>>(WZ, Zb, out, x);
}